// Round 7
// baseline (97.884 us; speedup 1.0000x reference)
//
#include <hip/hip_runtime.h>

typedef __attribute__((ext_vector_type(4))) int  i32x4;
typedef __attribute__((ext_vector_type(16))) int i32x16;

#define IC   256
#define OCH  128
#define BSZ  16
#define IH   64
#define IW   64
#define OH2  128
#define OW2  128
#define QMAXF 127.0f

// ws float-offset layout
#define WS_WSCALE 0        // 256 per-ic weight absmax
#define WS_APART  256      // 8*256 per-(bq,ic) act absmax partials
#define WS_QS     2304     // 256: x multiplier 1/(sc*sx)
#define WS_F      2816     // sx*sw
#define WS_WQ8    3072     // int8 [9][16][128][16] quantized weights (294912 B)

// ---------------- K1: per-channel absmax (partials over batch) ----------------
__global__ __launch_bounds__(256) void k_channel_scales(
        const float* __restrict__ x, const float* __restrict__ w,
        float* __restrict__ ws) {
    const int ic = blockIdx.x;
    const int bq = blockIdx.y;          // 0..7, two batches each
    const int t  = threadIdx.x;
    float amax = 0.f, wmax = 0.f;
    for (int bb = 2 * bq; bb < 2 * bq + 2; ++bb) {
        const float* xp = x + ((size_t)(bb * IC + ic)) * (IH * IW);
        for (int hw = t * 4; hw < IH * IW; hw += 1024) {
            float4 v = *(const float4*)(xp + hw);
            amax = fmaxf(amax, fmaxf(fmaxf(fabsf(v.x), fabsf(v.y)),
                                     fmaxf(fabsf(v.z), fabsf(v.w))));
        }
    }
    if (bq == 0)
        for (int j = t; j < OCH * 9; j += 256)
            wmax = fmaxf(wmax, fabsf(w[ic * (OCH * 9) + j]));
    __shared__ float r1[256], r2[256];
    r1[t] = wmax; r2[t] = amax;
    __syncthreads();
    for (int s = 128; s > 0; s >>= 1) {
        if (t < s) {
            r1[t] = fmaxf(r1[t], r1[t + s]);
            r2[t] = fmaxf(r2[t], r2[t + s]);
        }
        __syncthreads();
    }
    if (t == 0) {
        ws[WS_APART + bq * 256 + ic] = r2[0];
        if (bq == 0) ws[WS_WSCALE + ic] = r1[0];
    }
}

// ---- K2: finalize scales (redundant per block) + quantize weights -> int8 ----
// wq8 layout: [tap][kq(16)][oc(128)][16B]
__global__ __launch_bounds__(256) void k_quant_w(
        const float* __restrict__ w, float* __restrict__ ws) {
    __shared__ float scs[256], r1[256], r2[256];
    const int t = threadIdx.x;          // = ic for the scale phase
    float asc = 0.f;
    #pragma unroll
    for (int q8 = 0; q8 < 8; ++q8) asc = fmaxf(asc, ws[WS_APART + q8 * 256 + t]);
    const float wsc = ws[WS_WSCALE + t];
    float sc = sqrtf(asc) / sqrtf(wsc);
    if (sc == 0.f) sc = 1.f;
    r1[t] = wsc * sc;                   // elementwise max of |w*sc| (monotone)
    r2[t] = asc / sc;                   // elementwise max of |x/sc|
    __syncthreads();
    for (int s = 128; s > 0; s >>= 1) {
        if (t < s) {
            r1[t] = fmaxf(r1[t], r1[t + s]);
            r2[t] = fmaxf(r2[t], r2[t + s]);
        }
        __syncthreads();
    }
    float sw = r1[0] / QMAXF; if (sw == 0.f) sw = 1.f;
    float sx = r2[0] / QMAXF; if (sx == 0.f) sx = 1.f;
    scs[t] = sc / sw;                   // weight multiplier (same arithmetic as before)
    if (blockIdx.x == 0) {
        ws[WS_QS + t] = 1.f / (sc * sx);
        if (t == 0) ws[WS_F] = sx * sw;
    }
    __syncthreads();

    const int idx = blockIdx.x * 256 + t;   // [tap][kq][oc][e4]
    const int e0  = (idx & 3) * 4;
    const int oc  = (idx >> 2) & 127;
    const int kq  = (idx >> 9) & 15;
    const int tap = idx >> 13;
    unsigned pack = 0;
    #pragma unroll
    for (int c = 0; c < 4; ++c) {
        const int ic = kq * 16 + e0 + c;
        float q = rintf(w[((size_t)ic * OCH + oc) * 9 + tap] * scs[ic]);
        q = fminf(fmaxf(q, -128.f), 127.f);
        pack |= ((unsigned)((int)q & 255)) << (8 * c);
    }
    ((unsigned*)(ws + WS_WQ8))[idx] = pack;
}

// ---------------- K3: MFMA implicit-GEMM conv, swapped operands ----------------
// A-tile int8 [r(2)][v(66)][ic(256)], byte = (r*66+v)*256 + (ic ^ ((v&15)<<4))
__device__ __forceinline__ i32x4 load_a(const char* qa, int R, int S, int ks, int m, int lane) {
    const int v = m * 32 + (lane & 31) + S;
    const unsigned byte = (unsigned)((R * 66 + v) * 256)
        + (((unsigned)(ks * 32 + ((lane >> 5) << 4))) ^ (((unsigned)(v & 15)) << 4));
    return *(const i32x4*)(qa + byte);
}

__device__ __forceinline__ i32x4 load_b(const char* wq8, int tap, int ks, int oc, int lane) {
    const size_t off = ((size_t)((tap * 16 + ks * 2 + (lane >> 5)) * OCH + oc)) * 16;
    return *(const i32x4*)(wq8 + off);
}

template<int NT>
__device__ __forceinline__ void gemm_run(const char* qa, const char* wq8,
        const int (&taps)[NT], int oc0, int lane, i32x16 (&acc)[2]) {
    #pragma unroll
    for (int t = 0; t < NT; ++t) {
        const int tap = taps[t];
        const int R = tap < 3 ? 1 : 0;
        const int S = (tap % 3 == 0) ? 1 : 0;
        #pragma unroll
        for (int ks = 0; ks < 8; ++ks) {
            const i32x4 a0 = load_a(qa, R, S, ks, 0, lane);
            const i32x4 a1 = load_a(qa, R, S, ks, 1, lane);
            const i32x4 bb = load_b(wq8, tap, ks, oc0, lane);
            // swapped: weights are the M-operand -> D has row=oc, col=v
            acc[0] = __builtin_amdgcn_mfma_i32_32x32x32_i8(bb, a0, acc[0], 0, 0, 0);
            acc[1] = __builtin_amdgcn_mfma_i32_32x32x32_i8(bb, a1, acc[1], 0, 0, 0);
        }
    }
}

__global__ __launch_bounds__(512) void k_conv(
        const float* __restrict__ x, const float* __restrict__ bias,
        const float* __restrict__ ws, float* __restrict__ out) {
    __shared__ __align__(16) char smem[33792 + 512];
    char*  qa    = smem;
    float* sbias = (float*)(smem + 33792);

    const int tid  = threadIdx.x;
    // bijective XCD swizzle (1024 % 8 == 0): each XCD gets 128 consecutive f
    const int f0   = (blockIdx.x & 7) * 128 + (blockIdx.x >> 3);
    const int b    = f0 >> 6;
    const int u    = f0 & 63;        // output rows 2u, 2u+1
    const int lane = tid & 63;
    const int wid  = tid >> 6;       // 0..7
    const int q    = wid >> 1;       // oc quarter (32 wide)
    const int pa   = wid & 1;        // pairing

    // zero pad column v=64 (both r); load bias to LDS
    if (tid < 128)
        ((int*)(qa + ((tid >> 6) * 66 + 64) * 256))[tid & 63] = 0;
    else if (tid >= 384)
        sbias[tid - 384] = bias[tid - 384];

    // stage + quantize x rows u, u+1 -> int8 LDS (lane <-> col, coalesced);
    // per-iteration scale factors are wave-uniform -> s_loads
    for (int j = tid; j < 8192; j += 512) {
        const int v   = j & 63;
        const int icq = (j >> 6) & 63;
        const int r   = j >> 12;
        const int row = u + r;
        const int ic0 = icq * 4;
        unsigned pack = 0;
        if (row < IH) {
            const float* xp = x + (((size_t)(b * IC + ic0)) * IH + row) * IW + v;
            #pragma unroll
            for (int c = 0; c < 4; ++c) {
                float qv = fminf(fmaxf(rintf(xp[(size_t)c * IH * IW] * ws[WS_QS + ic0 + c]),
                                       -128.f), 127.f);
                pack |= ((unsigned)((int)qv & 255)) << (8 * c);
            }
        }
        *(unsigned*)(qa + (r * 66 + v) * 256 + ((unsigned)ic0 ^ (((unsigned)(v & 15)) << 4))) = pack;
    }
    __syncthreads();                 // the ONLY barrier

    const char* wq8 = (const char*)(ws + WS_WQ8);
    const int oc0 = q * 32 + (lane & 31);

    i32x16 accA[2], accB[2];         // A: row0 slot, B: row1 slot (64 regs)
    accA[0] = (i32x16)(0); accA[1] = (i32x16)(0);
    accB[0] = (i32x16)(0); accB[1] = (i32x16)(0);

    // pairing 0: (row0,par0) tap{4}    + (row1,par1) taps{0,2,6,8}
    // pairing 1: (row0,par1) taps{3,5} + (row1,par0) taps{1,7}
    if (pa == 0) {
        const int t0[1] = {4};
        gemm_run<1>(qa, wq8, t0, oc0, lane, accA);
        const int t1[4] = {0, 2, 6, 8};
        gemm_run<4>(qa, wq8, t1, oc0, lane, accB);
    } else {
        const int t0[2] = {3, 5};
        gemm_run<2>(qa, wq8, t0, oc0, lane, accA);
        const int t1[2] = {1, 7};
        gemm_run<2>(qa, wq8, t1, oc0, lane, accB);
    }

    // direct transposed stores: lane&31 = v, reg-pattern = oc
    const float fsc = ws[WS_F];
    const int vv  = lane & 31;
    const int ocq = q * 32 + 4 * (lane >> 5);
    #pragma unroll
    for (int reg = 0; reg < 16; ++reg) {
        const int oc = ocq + (reg & 3) + 8 * (reg >> 2);
        const float bv = sbias[oc];
        float* rowp = out + (((size_t)(b * OCH + oc)) * OH2 + 2 * u) * OW2;
        #pragma unroll
        for (int m = 0; m < 2; ++m) {
            const int ow0 = 2 * (m * 32 + vv);
            rowp[ow0 + pa]              = fmaf((float)accA[m][reg], fsc, bv);
            rowp[OW2 + ow0 + (pa ^ 1)]  = fmaf((float)accB[m][reg], fsc, bv);
        }
    }
}

extern "C" void kernel_launch(void* const* d_in, const int* in_sizes, int n_in,
                              void* d_out, int out_size, void* d_ws, size_t ws_size,
                              hipStream_t stream) {
    const float* x    = (const float*)d_in[0];
    const float* w    = (const float*)d_in[1];
    const float* bias = (const float*)d_in[2];
    float* ws  = (float*)d_ws;
    float* out = (float*)d_out;

    k_channel_scales<<<dim3(256, 8), 256, 0, stream>>>(x, w, ws);
    k_quant_w<<<288, 256, 0, stream>>>(w, ws);
    k_conv<<<1024, 512, 0, stream>>>(x, bias, ws, out);
}

// Round 8
// 90.488 us; speedup vs baseline: 1.0817x; 1.0817x over previous
//
#include <hip/hip_runtime.h>

typedef __attribute__((ext_vector_type(4))) int  i32x4;
typedef __attribute__((ext_vector_type(16))) int i32x16;

#define IC   256
#define OCH  128
#define BSZ  16
#define IH   64
#define IW   64
#define OH2  128
#define OW2  128
#define QMAXF 127.0f

// ws float-offset layout
#define WS_WSCALE 0        // 256 per-ic weight absmax
#define WS_APART  256      // 8*256 per-(bq,ic) act absmax partials
#define WS_QS     2304     // 256: x multiplier 1/(sc*sx)
#define WS_F      2816     // sx*sw
#define WS_WQ8    3072     // int8 [9][16][128][16] quantized weights (294912 B)

// ---------------- K1: per-channel absmax (partials over batch) ----------------
__global__ __launch_bounds__(256) void k_channel_scales(
        const float* __restrict__ x, const float* __restrict__ w,
        float* __restrict__ ws) {
    const int ic = blockIdx.x;
    const int bq = blockIdx.y;          // 0..7, two batches each
    const int t  = threadIdx.x;
    float amax = 0.f, wmax = 0.f;
    for (int bb = 2 * bq; bb < 2 * bq + 2; ++bb) {
        const float* xp = x + ((size_t)(bb * IC + ic)) * (IH * IW);
        for (int hw = t * 4; hw < IH * IW; hw += 1024) {
            float4 v = *(const float4*)(xp + hw);
            amax = fmaxf(amax, fmaxf(fmaxf(fabsf(v.x), fabsf(v.y)),
                                     fmaxf(fabsf(v.z), fabsf(v.w))));
        }
    }
    if (bq == 0)
        for (int j = t; j < OCH * 9; j += 256)
            wmax = fmaxf(wmax, fabsf(w[ic * (OCH * 9) + j]));
    __shared__ float r1[256], r2[256];
    r1[t] = wmax; r2[t] = amax;
    __syncthreads();
    for (int s = 128; s > 0; s >>= 1) {
        if (t < s) {
            r1[t] = fmaxf(r1[t], r1[t + s]);
            r2[t] = fmaxf(r2[t], r2[t + s]);
        }
        __syncthreads();
    }
    if (t == 0) {
        ws[WS_APART + bq * 256 + ic] = r2[0];
        if (bq == 0) ws[WS_WSCALE + ic] = r1[0];
    }
}

// ---- K2: finalize scales (redundant per block) + quantize weights -> int8 ----
// wq8 layout: [tap][kq(16)][oc(128)][16B]
__global__ __launch_bounds__(256) void k_quant_w(
        const float* __restrict__ w, float* __restrict__ ws) {
    __shared__ float scs[256], r1[256], r2[256];
    const int t = threadIdx.x;          // = ic for the scale phase
    float asc = 0.f;
    #pragma unroll
    for (int q8 = 0; q8 < 8; ++q8) asc = fmaxf(asc, ws[WS_APART + q8 * 256 + t]);
    const float wsc = ws[WS_WSCALE + t];
    float sc = sqrtf(asc) / sqrtf(wsc);
    if (sc == 0.f) sc = 1.f;
    r1[t] = wsc * sc;                   // elementwise max of |w*sc| (monotone)
    r2[t] = asc / sc;                   // elementwise max of |x/sc|
    __syncthreads();
    for (int s = 128; s > 0; s >>= 1) {
        if (t < s) {
            r1[t] = fmaxf(r1[t], r1[t + s]);
            r2[t] = fmaxf(r2[t], r2[t + s]);
        }
        __syncthreads();
    }
    float sw = r1[0] / QMAXF; if (sw == 0.f) sw = 1.f;
    float sx = r2[0] / QMAXF; if (sx == 0.f) sx = 1.f;
    scs[t] = sc / sw;                   // weight multiplier
    if (blockIdx.x == 0) {
        ws[WS_QS + t] = 1.f / (sc * sx);
        if (t == 0) ws[WS_F] = sx * sw;
    }
    __syncthreads();

    const int idx = blockIdx.x * 256 + t;   // [tap][kq][oc][e4]
    const int e0  = (idx & 3) * 4;
    const int oc  = (idx >> 2) & 127;
    const int kq  = (idx >> 9) & 15;
    const int tap = idx >> 13;
    unsigned pack = 0;
    #pragma unroll
    for (int c = 0; c < 4; ++c) {
        const int ic = kq * 16 + e0 + c;
        float q = rintf(w[((size_t)ic * OCH + oc) * 9 + tap] * scs[ic]);
        q = fminf(fmaxf(q, -128.f), 127.f);
        pack |= ((unsigned)((int)q & 255)) << (8 * c);
    }
    ((unsigned*)(ws + WS_WQ8))[idx] = pack;
}

// ---------------- K3: MFMA implicit-GEMM conv, swapped operands ----------------
// A-tile int8 [r(2)][v(66)][ic(256)], byte = (r*66+v)*256 + (ic ^ ((v&15)<<4))
__device__ __forceinline__ i32x4 load_a(const char* qa, int R, int S, int ks, int m, int lane) {
    const int v = m * 32 + (lane & 31) + S;
    const unsigned byte = (unsigned)((R * 66 + v) * 256)
        + (((unsigned)(ks * 32 + ((lane >> 5) << 4))) ^ (((unsigned)(v & 15)) << 4));
    return *(const i32x4*)(qa + byte);
}

__device__ __forceinline__ i32x4 load_b(const char* wq8, int tap, int ks, int oc, int lane) {
    const size_t off = ((size_t)((tap * 16 + ks * 2 + (lane >> 5)) * OCH + oc)) * 16;
    return *(const i32x4*)(wq8 + off);
}

template<int NT>
__device__ __forceinline__ void gemm_run(const char* qa, const char* wq8,
        const int (&taps)[NT], int oc0, int lane, i32x16 (&acc)[2]) {
    #pragma unroll
    for (int t = 0; t < NT; ++t) {
        const int tap = taps[t];
        const int R = tap < 3 ? 1 : 0;
        const int S = (tap % 3 == 0) ? 1 : 0;
        #pragma unroll
        for (int ks = 0; ks < 8; ++ks) {
            const i32x4 a0 = load_a(qa, R, S, ks, 0, lane);
            const i32x4 a1 = load_a(qa, R, S, ks, 1, lane);
            const i32x4 bb = load_b(wq8, tap, ks, oc0, lane);
            // swapped: weights are the M-operand -> D has row=oc, col=v
            acc[0] = __builtin_amdgcn_mfma_i32_32x32x32_i8(bb, a0, acc[0], 0, 0, 0);
            acc[1] = __builtin_amdgcn_mfma_i32_32x32x32_i8(bb, a1, acc[1], 0, 0, 0);
        }
    }
}

__global__ __launch_bounds__(512) void k_conv(
        const float* __restrict__ x, const float* __restrict__ bias,
        const float* __restrict__ ws, float* __restrict__ out) {
    __shared__ __align__(16) char smem[33792 + 512];
    char*  qa    = smem;
    float* sbias = (float*)(smem + 33792);

    const int tid  = threadIdx.x;
    // bijective XCD swizzle (1024 % 8 == 0): each XCD gets 128 consecutive f
    const int f0   = (blockIdx.x & 7) * 128 + (blockIdx.x >> 3);
    const int b    = f0 >> 6;
    const int u    = f0 & 63;        // output rows 2u, 2u+1
    const int lane = tid & 63;
    const int wid  = tid >> 6;       // 0..7
    const int q    = wid & 3;        // oc quarter (32 wide)
    const int r    = wid >> 2;       // output-row parity this wave owns

    // zero pad column v=64 (both r); load bias to LDS
    if (tid < 128)
        ((int*)(qa + ((tid >> 6) * 66 + 64) * 256))[tid & 63] = 0;
    else if (tid >= 384)
        sbias[tid - 384] = bias[tid - 384];

    // stage + quantize x rows u, u+1 -> int8 LDS (lane <-> col, coalesced);
    // per-iteration scale factors are wave-uniform -> s_loads
    for (int j = tid; j < 8192; j += 512) {
        const int v   = j & 63;
        const int icq = (j >> 6) & 63;
        const int rr  = j >> 12;
        const int row = u + rr;
        const int ic0 = icq * 4;
        unsigned pack = 0;
        if (row < IH) {
            const float* xp = x + (((size_t)(b * IC + ic0)) * IH + row) * IW + v;
            #pragma unroll
            for (int c = 0; c < 4; ++c) {
                float qv = fminf(fmaxf(rintf(xp[(size_t)c * IH * IW] * ws[WS_QS + ic0 + c]),
                                       -128.f), 127.f);
                pack |= ((unsigned)((int)qv & 255)) << (8 * c);
            }
        }
        *(unsigned*)(qa + (rr * 66 + v) * 256 + ((unsigned)ic0 ^ (((unsigned)(v & 15)) << 4))) = pack;
    }
    __syncthreads();                 // the ONLY barrier

    const char* wq8 = (const char*)(ws + WS_WQ8);
    const int oc0 = q * 32 + (lane & 31);

    // both parities of this wave's output row: 4 x i32x16 = 64 VGPR (spill-free)
    i32x16 accP0[2], accP1[2];
    accP0[0] = (i32x16)(0); accP0[1] = (i32x16)(0);
    accP1[0] = (i32x16)(0); accP1[1] = (i32x16)(0);

    // row 0 (oh=2u):   par0 tap{4},     par1 taps{3,5}
    // row 1 (oh=2u+1): par0 taps{1,7},  par1 taps{0,2,6,8}
    if (r == 0) {
        const int t0[1] = {4};
        gemm_run<1>(qa, wq8, t0, oc0, lane, accP0);
        const int t1[2] = {3, 5};
        gemm_run<2>(qa, wq8, t1, oc0, lane, accP1);
    } else {
        const int t0[2] = {1, 7};
        gemm_run<2>(qa, wq8, t0, oc0, lane, accP0);
        const int t1[4] = {0, 2, 6, 8};
        gemm_run<4>(qa, wq8, t1, oc0, lane, accP1);
    }

    // dense float2 stores: lane&31 = v, both parities in-lane -> ow {2v, 2v+1}
    const float fsc = ws[WS_F];
    const int vv  = lane & 31;
    const int ocq = q * 32 + 4 * (lane >> 5);
    const int oh  = 2 * u + r;
    #pragma unroll
    for (int reg = 0; reg < 16; ++reg) {
        const int oc = ocq + (reg & 3) + 8 * (reg >> 2);
        const float bv = sbias[oc];
        float* rowp = out + (((size_t)(b * OCH + oc)) * OH2 + oh) * OW2;
        #pragma unroll
        for (int m = 0; m < 2; ++m) {
            float2 o;
            o.x = fmaf((float)accP0[m][reg], fsc, bv);
            o.y = fmaf((float)accP1[m][reg], fsc, bv);
            *(float2*)(rowp + 2 * (m * 32 + vv)) = o;
        }
    }
}

extern "C" void kernel_launch(void* const* d_in, const int* in_sizes, int n_in,
                              void* d_out, int out_size, void* d_ws, size_t ws_size,
                              hipStream_t stream) {
    const float* x    = (const float*)d_in[0];
    const float* w    = (const float*)d_in[1];
    const float* bias = (const float*)d_in[2];
    float* ws  = (float*)d_ws;
    float* out = (float*)d_out;

    k_channel_scales<<<dim3(256, 8), 256, 0, stream>>>(x, w, ws);
    k_quant_w<<<288, 256, 0, stream>>>(w, ws);
    k_conv<<<1024, 512, 0, stream>>>(x, bias, ws, out);
}